// Round 17
// baseline (127.205 us; speedup 1.0000x reference)
//
#include <hip/hip_runtime.h>
#include <hip/hip_fp16.h>

#define Bsz 256
#define Nn  1152
#define Kk  10
#define NT  768      // 12 waves/block; LDS exactly 80 KB -> 2 blocks/CU = 24 waves
#define NW  12
#define S4  1154     // uint stride per o-pair row (mod 32 = 2; uint2-aligned)

#define W_ELEMS (Kk*Nn*128)     // 1474560
#define U_ELEMS (Bsz*Nn*8)      // 2359296
#define WCELLS  (Kk*Nn)         // 11520 cells of 8x16
#define WBLKS   (WCELLS/16)     // 720 transpose blocks
#define UBLKS   (U_ELEMS/8/256) // 1152 u-convert blocks

typedef _Float16 hf2_t __attribute__((ext_vector_type(2)));

static __device__ __forceinline__ unsigned pkh2(float x, float y) {
    __half2 h = __floats2half2_rn(x, y);
    return *reinterpret_cast<unsigned*>(&h);
}
// v_dot2_f32_f16: c += a.lo*b.lo + a.hi*b.hi (f32 accumulate, 1 inst)
static __device__ __forceinline__ float fdot2u(unsigned a, unsigned b, float c) {
    union { unsigned u; hf2_t h; } A, B;
    A.u = a; B.u = b;
    return __builtin_amdgcn_fdot2(A.h, B.h, c, false);
}
// Within-wave LDS write->read ordering (no s_barrier for wave-local data)
static __device__ __forceinline__ void wave_lds_fence() {
    __builtin_amdgcn_sched_barrier(0);
    asm volatile("s_waitcnt lgkmcnt(0)" ::: "memory");
    __builtin_amdgcn_sched_barrier(0);
}

#define PERM_LO 0x01000504u   // perm(a,b,LO) = half2(lo = lo16(a), hi = lo16(b))
#define PERM_HI 0x03020706u
#define ONE2    0x3C003C00u   // half2(1, 1)

// W: fp32 [K][N][8 i][16 o] -> Wh: fp16 [K][N][16 o][8 i] (per-cell transpose so
// each o-row is 4 half2 i-pairs, dot2-ready — kills phase-1 perms).
// u: fp32 -> fp16, layout unchanged. (R1/R7-verified transpose cvt.)
__global__ void cvt_kernel(const float* __restrict__ W, const float* __restrict__ u,
                           unsigned* __restrict__ Wh, __half2* __restrict__ uh) {
    const int t = threadIdx.x;
    if ((int)blockIdx.x < WBLKS) {
        __shared__ float ws[16 * 132];
        const size_t base = (size_t)blockIdx.x * (16 * 128);
        const float4* p = (const float4*)(W + base) + t * 2;
        const float4 x = p[0], y = p[1];
        {
            const int e = t * 8;
            float* d = ws + (e >> 7) * 132 + (e & 127);
            d[0]=x.x; d[1]=x.y; d[2]=x.z; d[3]=x.w;
            d[4]=y.x; d[5]=y.y; d[6]=y.z; d[7]=y.w;
        }
        __syncthreads();
        const int c = t >> 4, o = t & 15;        // one o-row per thread
        const float* s = ws + c * 132 + o;
        uint4 r;
        r.x = pkh2(s[0*16], s[1*16]);
        r.y = pkh2(s[2*16], s[3*16]);
        r.z = pkh2(s[4*16], s[5*16]);
        r.w = pkh2(s[6*16], s[7*16]);
        *(uint4*)(Wh + ((size_t)blockIdx.x * 16 + c) * 64 + o * 4) = r;
    } else {
        const int j = ((int)blockIdx.x - WBLKS) * 256 + t;   // < 294912
        const float4* p = (const float4*)u + (size_t)j * 2;
        __half2* o = uh + (size_t)j * 4;
        const float4 a = p[0], b = p[1];
        o[0] = __floats2half2_rn(a.x, a.y);
        o[1] = __floats2half2_rn(a.z, a.w);
        o[2] = __floats2half2_rn(b.x, b.y);
        o[3] = __floats2half2_rn(b.z, b.w);
    }
}

// One block per (b-pair, k), 12 waves (R16-verified structure, 58 us). Wave w owns
// rows n = 96w + 32rr + pr. Phase 1 loads each W o-row ONCE (transposed layout,
// per-o chained dot2, NO perms) and produces u_hat for BOTH b's into LDS.
// Routing: even lanes route b0, odd lanes b1; per-b wave max via parity-preserving
// shfl_xor 2..32; s-scan covers both b's; cross-wave exp(m_w - M) rescale at
// finalize. 3 barriers + wave-local fences. WRITE_SIZE is the spill tripwire.
template<bool HALF>
__global__ __launch_bounds__(NT, 6)
void digitcaps_kernel(const float* __restrict__ u32, const float* __restrict__ W32,
                      const __half* __restrict__ uh, const __half* __restrict__ Wh,
                      float* __restrict__ out)
{
    const int t    = threadIdx.x;
    const int lane = t & 63;
    const int wav  = t >> 6;             // 0..11
    const int oh   = lane & 1;
    const int pr   = lane >> 1;          // 0..31
    const int bg   = blockIdx.x;         // 0..127
    const int k    = blockIdx.y;         // 0..9
    const int b0   = 2 * bg;
    const int b1   = 2 * bg + 1;

    __shared__ unsigned uhS2[2][8][S4];      // 73856 B  [b][o-pair row][col n]
    __shared__ unsigned cSu[2][Nn / 2];      // 4608 B   [b] e per n (half), uint-paired
    __shared__ float    redS[2][2][NW][18];  // 3456 B   [buf][b][wav][s0..15, d, m_w]
    // total exactly 81920 B -> 2 blocks/CU (24 waves) iff VGPR <= 85

    // ---------------- Phase 1: u_hat = u . W for BOTH b's, W loaded once ----------------
    #pragma unroll
    for (int rr = 0; rr < 3; ++rr) {
        const int n = 96 * wav + 32 * rr + pr;
        float a0[8], a1[8];
        if (HALF) {
            const uint4 uq0 = *(const uint4*)(uh + ((size_t)b0 * Nn + n) * 8);
            const uint4 uq1 = *(const uint4*)(uh + ((size_t)b1 * Nn + n) * 8);
            // cell = 16 uint4 (16 o-rows of 4 half2 i-pairs); this thread: 8 rows at oh*8
            const uint4* wp = (const uint4*)Wh + ((size_t)(k * Nn + n)) * 16 + oh * 8;
            #pragma unroll
            for (int o = 0; o < 8; ++o) {
                const uint4 w = wp[o];
                a0[o] = fdot2u(w.w, uq0.w, fdot2u(w.z, uq0.z,
                        fdot2u(w.y, uq0.y, fdot2u(w.x, uq0.x, 0.f))));
                a1[o] = fdot2u(w.w, uq1.w, fdot2u(w.z, uq1.z,
                        fdot2u(w.y, uq1.y, fdot2u(w.x, uq1.x, 0.f))));
            }
        } else {
            float ua0[8], ua1[8];
            const float4* up0 = (const float4*)(u32 + ((size_t)b0 * Nn + n) * 8);
            const float4* up1 = (const float4*)(u32 + ((size_t)b1 * Nn + n) * 8);
            const float4 x0 = up0[0], x1 = up0[1];
            const float4 y0 = up1[0], y1 = up1[1];
            ua0[0]=x0.x; ua0[1]=x0.y; ua0[2]=x0.z; ua0[3]=x0.w;
            ua0[4]=x1.x; ua0[5]=x1.y; ua0[6]=x1.z; ua0[7]=x1.w;
            ua1[0]=y0.x; ua1[1]=y0.y; ua1[2]=y0.z; ua1[3]=y0.w;
            ua1[4]=y1.x; ua1[5]=y1.y; ua1[6]=y1.z; ua1[7]=y1.w;
            #pragma unroll
            for (int o = 0; o < 8; ++o) { a0[o] = 0.f; a1[o] = 0.f; }
            #pragma unroll
            for (int i = 0; i < 8; ++i) {
                const float4* wp = (const float4*)(W32 + ((size_t)k * Nn + n) * 128) + oh * 2 + i * 4;
                const float4 w0 = wp[0], w1 = wp[1];
                float wv[8];
                wv[0]=w0.x; wv[1]=w0.y; wv[2]=w0.z; wv[3]=w0.w;
                wv[4]=w1.x; wv[5]=w1.y; wv[6]=w1.z; wv[7]=w1.w;
                const float x = ua0[i], y = ua1[i];
                #pragma unroll
                for (int o = 0; o < 8; ++o) { a0[o] += x * wv[o]; a1[o] += y * wv[o]; }
            }
        }
        #pragma unroll
        for (int jj = 0; jj < 4; ++jj) {
            uhS2[0][oh * 4 + jj][n] = pkh2(a0[2*jj], a0[2*jj+1]);
            uhS2[1][oh * 4 + jj][n] = pkh2(a1[2*jj], a1[2*jj+1]);
        }
    }
    wave_lds_fence();   // each wave's scans read only its own 96-row region

    // ---------------- Phase 2: routing (lane parity = which b it routes) ----------------
    float lg[3] = {0.f, 0.f, 0.f};   // logits for this lane's b (= oh) rows
    unsigned vhsel[8];               // v for b = oh, packed half2 (all 8 o-pairs)
    const int j_s = lane & 7;
    const int g_s = lane >> 3;

    #pragma unroll
    for (int it = 0; it < 3; ++it) {
        float m_w = 0.f;
        if (it > 0) {
            // ---- a-scan: lane routes its b over its pair's 3 rows (LDS full-o reads) ----
            #pragma unroll
            for (int rr = 0; rr < 3; ++rr) {
                const int n = 96 * wav + 32 * rr + pr;
                float acc = 0.f;
                #pragma unroll
                for (int jj = 0; jj < 8; ++jj)
                    acc = fdot2u(uhS2[oh][jj][n], vhsel[jj], acc);
                lg[rr] += acc;
            }
            // ---- per-wave per-b max: parity-preserving reduce (offsets 2..32) ----
            float m = fmaxf(fmaxf(lg[0], lg[1]), lg[2]);
            #pragma unroll
            for (int off = 2; off <= 32; off <<= 1)
                m = fmaxf(m, __shfl_xor(m, off));
            m_w = m;                 // even lanes: m_b0; odd lanes: m_b1
            // ---- e -> cSu[oh] (wave-local; e <= 1, fp16-safe) ----
            #pragma unroll
            for (int rr = 0; rr < 3; ++rr) {
                const int n = 96 * wav + 32 * rr + pr;
                ((__half*)cSu[oh])[n] = __float2half(__expf(lg[rr] - m_w));
            }
            wave_lds_fence();        // readers are this same wave
        }

        // ---- s-scan: BOTH b's over wave's 96 rows, pairs (n0, n0+1) ----
        float2 sp0 = {0.f, 0.f}, sp1 = {0.f, 0.f};
        float dp0 = 0.f, dp1 = 0.f;
        #pragma unroll
        for (int cc = 0; cc < 6; ++cc) {
            const int n0 = 96 * wav + 2 * (g_s + 8 * cc);
            unsigned cp0, cp1;
            if (it == 0) { cp0 = ONE2; cp1 = ONE2; }
            else { cp0 = cSu[0][n0 >> 1]; cp1 = cSu[1][n0 >> 1]; }
            const uint2 q0 = *(const uint2*)&uhS2[0][j_s][n0];
            const uint2 q1 = *(const uint2*)&uhS2[1][j_s][n0];
            const unsigned px0 = __builtin_amdgcn_perm(q0.x, q0.y, PERM_LO);
            const unsigned py0 = __builtin_amdgcn_perm(q0.x, q0.y, PERM_HI);
            const unsigned px1 = __builtin_amdgcn_perm(q1.x, q1.y, PERM_LO);
            const unsigned py1 = __builtin_amdgcn_perm(q1.x, q1.y, PERM_HI);
            sp0.x = fdot2u(px0, cp0, sp0.x);
            sp0.y = fdot2u(py0, cp0, sp0.y);
            sp1.x = fdot2u(px1, cp1, sp1.x);
            sp1.y = fdot2u(py1, cp1, sp1.y);
            dp0   = fdot2u(cp0, ONE2, dp0);
            dp1   = fdot2u(cp1, ONE2, dp1);
        }
        #pragma unroll
        for (int off = 8; off <= 32; off <<= 1) {
            sp0.x += __shfl_xor(sp0.x, off);
            sp0.y += __shfl_xor(sp0.y, off);
            sp1.x += __shfl_xor(sp1.x, off);
            sp1.y += __shfl_xor(sp1.y, off);
            dp0   += __shfl_xor(dp0,   off);
            dp1   += __shfl_xor(dp1,   off);
        }
        const int buf = it & 1;
        if (lane < 8) {
            redS[buf][0][wav][2 * j_s    ] = sp0.x;
            redS[buf][0][wav][2 * j_s + 1] = sp0.y;
            redS[buf][1][wav][2 * j_s    ] = sp1.x;
            redS[buf][1][wav][2 * j_s + 1] = sp1.y;
        }
        if (lane == 0)
            *(float2*)&redS[buf][0][wav][16] = make_float2(dp0, m_w);  // m_w = m_b0 here
        if (lane == 1)
            *(float2*)&redS[buf][1][wav][16] = make_float2(dp1, m_w);  // m_w = m_b1 here
        __syncthreads();                               // the ONLY barrier per iter

        // ---- finalize: per-b cross-wave rescale + squash (redundant per wave) ----
        if (it < 2 || wav == 0) {
            const int bsel = (lane >> 4) & 1;
            const int o    = lane & 15;
            float M = redS[buf][bsel][0][17];
            #pragma unroll
            for (int w = 1; w < NW; ++w) M = fmaxf(M, redS[buf][bsel][w][17]);
            float s = 0.f, d = 0.f;
            #pragma unroll
            for (int w = 0; w < NW; ++w) {
                const float2 dm = *(const float2*)&redS[buf][bsel][w][16];
                const float sc = (it == 0) ? 1.f : __expf(dm.y - M);
                s += sc * redS[buf][bsel][w][o];
                d += sc * dm.x;
            }
            s /= d;
            float s2 = s * s;
            #pragma unroll
            for (int off = 1; off <= 8; off <<= 1) s2 += __shfl_xor(s2, off);
            const float scale = (s2 / (1.f + s2)) * rsqrtf(fmaxf(s2, 1e-30f));
            const float v = s * scale;
            if (it == 2) {
                if (wav == 0 && lane < 32)
                    out[((size_t)k * Bsz + b0 + bsel) * 16 + o] = v;
            } else {
                // lane's own b half: v_b0 in lanes 0-15, v_b1 in lanes 16-31.
                // runtime shfl lane index ok; array subscript jj static.
                #pragma unroll
                for (int jj = 0; jj < 8; ++jj)
                    vhsel[jj] = pkh2(__shfl(v, 16 * oh + 2 * jj),
                                     __shfl(v, 16 * oh + 2 * jj + 1));
            }
        }
    }
}

extern "C" void kernel_launch(void* const* d_in, const int* in_sizes, int n_in,
                              void* d_out, int out_size, void* d_ws, size_t ws_size,
                              hipStream_t stream) {
    const float* u = (const float*)d_in[0];
    const float* W = (const float*)d_in[1];
    float* out = (float*)d_out;
    const size_t need = (size_t)(W_ELEMS + U_ELEMS) * sizeof(__half);
    if (ws_size >= need) {
        __half* Wh = (__half*)d_ws;
        __half* uh = (__half*)((char*)d_ws + (size_t)W_ELEMS * sizeof(__half));
        cvt_kernel<<<dim3(WBLKS + UBLKS), dim3(256), 0, stream>>>(
            W, u, (unsigned*)Wh, (__half2*)uh);
        digitcaps_kernel<true><<<dim3(128, 10), dim3(NT), 0, stream>>>(
            nullptr, nullptr, uh, Wh, out);
    } else {
        digitcaps_kernel<false><<<dim3(128, 10), dim3(NT), 0, stream>>>(
            u, W, nullptr, nullptr, out);
    }
}

// Round 18
// 115.441 us; speedup vs baseline: 1.1019x; 1.1019x over previous
//
#include <hip/hip_runtime.h>
#include <hip/hip_fp16.h>

#define Bsz 256
#define Nn  1152
#define Kk  10
#define NT  768      // 12 waves/block; LDS exactly 80 KB -> 2 blocks/CU = 24 waves
#define NW  12
#define S4  1154     // uint stride per o-pair row (mod 32 = 2; uint2-aligned)

#define W_ELEMS (Kk*Nn*128)     // 1474560
#define U_ELEMS (Bsz*Nn*8)      // 2359296
#define WCELLS  (Kk*Nn)         // 11520 cells of 8x16
#define WBLKS   (WCELLS/16)     // 720 transpose blocks
#define UBLKS   (U_ELEMS/8/256) // 1152 u-convert blocks

typedef _Float16 hf2_t __attribute__((ext_vector_type(2)));

static __device__ __forceinline__ unsigned pkh2(float x, float y) {
    __half2 h = __floats2half2_rn(x, y);
    return *reinterpret_cast<unsigned*>(&h);
}
// v_dot2_f32_f16: c += a.lo*b.lo + a.hi*b.hi (f32 accumulate, 1 inst)
static __device__ __forceinline__ float fdot2u(unsigned a, unsigned b, float c) {
    union { unsigned u; hf2_t h; } A, B;
    A.u = a; B.u = b;
    return __builtin_amdgcn_fdot2(A.h, B.h, c, false);
}
// Within-wave LDS write->read ordering (no s_barrier for wave-local data)
static __device__ __forceinline__ void wave_lds_fence() {
    __builtin_amdgcn_sched_barrier(0);
    asm volatile("s_waitcnt lgkmcnt(0)" ::: "memory");
    __builtin_amdgcn_sched_barrier(0);
}

#define PERM_LO 0x01000504u   // perm(a,b,LO) = half2(lo = lo16(a), hi = lo16(b))
#define PERM_HI 0x03020706u
#define ONE2    0x3C003C00u   // half2(1, 1)

// W: fp32 [K][N][8 i][16 o] -> Wh: fp16, per-cell transposed AND oh-interleaved:
// the uint4 (4 half2 i-pairs) for o-row `o` sits at cell slot (o&7)*2 + (o>>3).
// Phase-1 thread (pr, oh) load j then reads slot j*2+oh -> lane-pair addresses
// contiguous 32 B (R16's coalescing) while staying dot2-ready (R17's math).
__global__ void cvt_kernel(const float* __restrict__ W, const float* __restrict__ u,
                           unsigned* __restrict__ Wh, __half2* __restrict__ uh) {
    const int t = threadIdx.x;
    if ((int)blockIdx.x < WBLKS) {
        __shared__ float ws[16 * 132];
        const size_t base = (size_t)blockIdx.x * (16 * 128);
        const float4* p = (const float4*)(W + base) + t * 2;
        const float4 x = p[0], y = p[1];
        {
            const int e = t * 8;
            float* d = ws + (e >> 7) * 132 + (e & 127);
            d[0]=x.x; d[1]=x.y; d[2]=x.z; d[3]=x.w;
            d[4]=y.x; d[5]=y.y; d[6]=y.z; d[7]=y.w;
        }
        __syncthreads();
        const int c = t >> 4, o = t & 15;        // one o-row per thread
        const float* s = ws + c * 132 + o;
        uint4 r;
        r.x = pkh2(s[0*16], s[1*16]);
        r.y = pkh2(s[2*16], s[3*16]);
        r.z = pkh2(s[4*16], s[5*16]);
        r.w = pkh2(s[6*16], s[7*16]);
        const int slot = (o & 7) * 2 + (o >> 3);         // oh-interleaved slot
        *(uint4*)(Wh + (((size_t)blockIdx.x * 16 + c) * 16 + slot) * 4) = r;
    } else {
        const int j = ((int)blockIdx.x - WBLKS) * 256 + t;   // < 294912
        const float4* p = (const float4*)u + (size_t)j * 2;
        __half2* o = uh + (size_t)j * 4;
        const float4 a = p[0], b = p[1];
        o[0] = __floats2half2_rn(a.x, a.y);
        o[1] = __floats2half2_rn(a.z, a.w);
        o[2] = __floats2half2_rn(b.x, b.y);
        o[3] = __floats2half2_rn(b.z, b.w);
    }
}

// One block per (b-pair, k), 12 waves (R16-verified structure). Wave w owns rows
// n = 96w + 32rr + pr. Phase 1: W loaded once for BOTH b's, oh-interleaved
// transposed layout -> 32B-contiguous lane pairs AND perm-free chained dot2.
// Routing: even lanes route b0, odd lanes b1; per-b wave max via parity-preserving
// shfl_xor 2..32; s-scan covers both b's; cross-wave exp(m_w - M) rescale at
// finalize. 3 barriers + wave-local fences. WRITE_SIZE is the spill tripwire.
template<bool HALF>
__global__ __launch_bounds__(NT, 6)
void digitcaps_kernel(const float* __restrict__ u32, const float* __restrict__ W32,
                      const __half* __restrict__ uh, const __half* __restrict__ Wh,
                      float* __restrict__ out)
{
    const int t    = threadIdx.x;
    const int lane = t & 63;
    const int wav  = t >> 6;             // 0..11
    const int oh   = lane & 1;
    const int pr   = lane >> 1;          // 0..31
    const int bg   = blockIdx.x;         // 0..127
    const int k    = blockIdx.y;         // 0..9
    const int b0   = 2 * bg;
    const int b1   = 2 * bg + 1;

    __shared__ unsigned uhS2[2][8][S4];      // 73856 B  [b][o-pair row][col n]
    __shared__ unsigned cSu[2][Nn / 2];      // 4608 B   [b] e per n (half), uint-paired
    __shared__ float    redS[2][2][NW][18];  // 3456 B   [buf][b][wav][s0..15, d, m_w]
    // total exactly 81920 B -> 2 blocks/CU (24 waves) iff VGPR <= 85

    // ---------------- Phase 1: u_hat = u . W for BOTH b's, W loaded once ----------------
    #pragma unroll
    for (int rr = 0; rr < 3; ++rr) {
        const int n = 96 * wav + 32 * rr + pr;
        float a0[8], a1[8];
        if (HALF) {
            const uint4 uq0 = *(const uint4*)(uh + ((size_t)b0 * Nn + n) * 8);
            const uint4 uq1 = *(const uint4*)(uh + ((size_t)b1 * Nn + n) * 8);
            // cell = 16 uint4, oh-interleaved: load j for this thread = slot 2j+oh.
            const uint4* wp = (const uint4*)Wh + ((size_t)(k * Nn + n)) * 16;
            #pragma unroll
            for (int o = 0; o < 8; ++o) {            // o = local row j; global row 8*oh+o
                const uint4 w = wp[2 * o + oh];
                a0[o] = fdot2u(w.w, uq0.w, fdot2u(w.z, uq0.z,
                        fdot2u(w.y, uq0.y, fdot2u(w.x, uq0.x, 0.f))));
                a1[o] = fdot2u(w.w, uq1.w, fdot2u(w.z, uq1.z,
                        fdot2u(w.y, uq1.y, fdot2u(w.x, uq1.x, 0.f))));
            }
        } else {
            float ua0[8], ua1[8];
            const float4* up0 = (const float4*)(u32 + ((size_t)b0 * Nn + n) * 8);
            const float4* up1 = (const float4*)(u32 + ((size_t)b1 * Nn + n) * 8);
            const float4 x0 = up0[0], x1 = up0[1];
            const float4 y0 = up1[0], y1 = up1[1];
            ua0[0]=x0.x; ua0[1]=x0.y; ua0[2]=x0.z; ua0[3]=x0.w;
            ua0[4]=x1.x; ua0[5]=x1.y; ua0[6]=x1.z; ua0[7]=x1.w;
            ua1[0]=y0.x; ua1[1]=y0.y; ua1[2]=y0.z; ua1[3]=y0.w;
            ua1[4]=y1.x; ua1[5]=y1.y; ua1[6]=y1.z; ua1[7]=y1.w;
            #pragma unroll
            for (int o = 0; o < 8; ++o) { a0[o] = 0.f; a1[o] = 0.f; }
            #pragma unroll
            for (int i = 0; i < 8; ++i) {
                const float4* wp = (const float4*)(W32 + ((size_t)k * Nn + n) * 128) + oh * 2 + i * 4;
                const float4 w0 = wp[0], w1 = wp[1];
                float wv[8];
                wv[0]=w0.x; wv[1]=w0.y; wv[2]=w0.z; wv[3]=w0.w;
                wv[4]=w1.x; wv[5]=w1.y; wv[6]=w1.z; wv[7]=w1.w;
                const float x = ua0[i], y = ua1[i];
                #pragma unroll
                for (int o = 0; o < 8; ++o) { a0[o] += x * wv[o]; a1[o] += y * wv[o]; }
            }
        }
        #pragma unroll
        for (int jj = 0; jj < 4; ++jj) {
            uhS2[0][oh * 4 + jj][n] = pkh2(a0[2*jj], a0[2*jj+1]);
            uhS2[1][oh * 4 + jj][n] = pkh2(a1[2*jj], a1[2*jj+1]);
        }
    }
    wave_lds_fence();   // each wave's scans read only its own 96-row region

    // ---------------- Phase 2: routing (lane parity = which b it routes) ----------------
    float lg[3] = {0.f, 0.f, 0.f};   // logits for this lane's b (= oh) rows
    unsigned vhsel[8];               // v for b = oh, packed half2 (all 8 o-pairs)
    const int j_s = lane & 7;
    const int g_s = lane >> 3;

    #pragma unroll
    for (int it = 0; it < 3; ++it) {
        float m_w = 0.f;
        if (it > 0) {
            // ---- a-scan: lane routes its b over its pair's 3 rows (LDS full-o reads) ----
            #pragma unroll
            for (int rr = 0; rr < 3; ++rr) {
                const int n = 96 * wav + 32 * rr + pr;
                float acc = 0.f;
                #pragma unroll
                for (int jj = 0; jj < 8; ++jj)
                    acc = fdot2u(uhS2[oh][jj][n], vhsel[jj], acc);
                lg[rr] += acc;
            }
            // ---- per-wave per-b max: parity-preserving reduce (offsets 2..32) ----
            float m = fmaxf(fmaxf(lg[0], lg[1]), lg[2]);
            #pragma unroll
            for (int off = 2; off <= 32; off <<= 1)
                m = fmaxf(m, __shfl_xor(m, off));
            m_w = m;                 // even lanes: m_b0; odd lanes: m_b1
            // ---- e -> cSu[oh] (wave-local; e <= 1, fp16-safe) ----
            #pragma unroll
            for (int rr = 0; rr < 3; ++rr) {
                const int n = 96 * wav + 32 * rr + pr;
                ((__half*)cSu[oh])[n] = __float2half(__expf(lg[rr] - m_w));
            }
            wave_lds_fence();        // readers are this same wave
        }

        // ---- s-scan: BOTH b's over wave's 96 rows, pairs (n0, n0+1) ----
        float2 sp0 = {0.f, 0.f}, sp1 = {0.f, 0.f};
        float dp0 = 0.f, dp1 = 0.f;
        #pragma unroll
        for (int cc = 0; cc < 6; ++cc) {
            const int n0 = 96 * wav + 2 * (g_s + 8 * cc);
            unsigned cp0, cp1;
            if (it == 0) { cp0 = ONE2; cp1 = ONE2; }
            else { cp0 = cSu[0][n0 >> 1]; cp1 = cSu[1][n0 >> 1]; }
            const uint2 q0 = *(const uint2*)&uhS2[0][j_s][n0];
            const uint2 q1 = *(const uint2*)&uhS2[1][j_s][n0];
            const unsigned px0 = __builtin_amdgcn_perm(q0.x, q0.y, PERM_LO);
            const unsigned py0 = __builtin_amdgcn_perm(q0.x, q0.y, PERM_HI);
            const unsigned px1 = __builtin_amdgcn_perm(q1.x, q1.y, PERM_LO);
            const unsigned py1 = __builtin_amdgcn_perm(q1.x, q1.y, PERM_HI);
            sp0.x = fdot2u(px0, cp0, sp0.x);
            sp0.y = fdot2u(py0, cp0, sp0.y);
            sp1.x = fdot2u(px1, cp1, sp1.x);
            sp1.y = fdot2u(py1, cp1, sp1.y);
            dp0   = fdot2u(cp0, ONE2, dp0);
            dp1   = fdot2u(cp1, ONE2, dp1);
        }
        #pragma unroll
        for (int off = 8; off <= 32; off <<= 1) {
            sp0.x += __shfl_xor(sp0.x, off);
            sp0.y += __shfl_xor(sp0.y, off);
            sp1.x += __shfl_xor(sp1.x, off);
            sp1.y += __shfl_xor(sp1.y, off);
            dp0   += __shfl_xor(dp0,   off);
            dp1   += __shfl_xor(dp1,   off);
        }
        const int buf = it & 1;
        if (lane < 8) {
            redS[buf][0][wav][2 * j_s    ] = sp0.x;
            redS[buf][0][wav][2 * j_s + 1] = sp0.y;
            redS[buf][1][wav][2 * j_s    ] = sp1.x;
            redS[buf][1][wav][2 * j_s + 1] = sp1.y;
        }
        if (lane == 0)
            *(float2*)&redS[buf][0][wav][16] = make_float2(dp0, m_w);  // m_w = m_b0 here
        if (lane == 1)
            *(float2*)&redS[buf][1][wav][16] = make_float2(dp1, m_w);  // m_w = m_b1 here
        __syncthreads();                               // the ONLY barrier per iter

        // ---- finalize: per-b cross-wave rescale + squash (redundant per wave) ----
        if (it < 2 || wav == 0) {
            const int bsel = (lane >> 4) & 1;
            const int o    = lane & 15;
            float M = redS[buf][bsel][0][17];
            #pragma unroll
            for (int w = 1; w < NW; ++w) M = fmaxf(M, redS[buf][bsel][w][17]);
            float s = 0.f, d = 0.f;
            #pragma unroll
            for (int w = 0; w < NW; ++w) {
                const float2 dm = *(const float2*)&redS[buf][bsel][w][16];
                const float sc = (it == 0) ? 1.f : __expf(dm.y - M);
                s += sc * redS[buf][bsel][w][o];
                d += sc * dm.x;
            }
            s /= d;
            float s2 = s * s;
            #pragma unroll
            for (int off = 1; off <= 8; off <<= 1) s2 += __shfl_xor(s2, off);
            const float scale = (s2 / (1.f + s2)) * rsqrtf(fmaxf(s2, 1e-30f));
            const float v = s * scale;
            if (it == 2) {
                if (wav == 0 && lane < 32)
                    out[((size_t)k * Bsz + b0 + bsel) * 16 + o] = v;
            } else {
                // lane's own b half: v_b0 in lanes 0-15, v_b1 in lanes 16-31.
                // runtime shfl lane index ok; array subscript jj static.
                #pragma unroll
                for (int jj = 0; jj < 8; ++jj)
                    vhsel[jj] = pkh2(__shfl(v, 16 * oh + 2 * jj),
                                     __shfl(v, 16 * oh + 2 * jj + 1));
            }
        }
    }
}

extern "C" void kernel_launch(void* const* d_in, const int* in_sizes, int n_in,
                              void* d_out, int out_size, void* d_ws, size_t ws_size,
                              hipStream_t stream) {
    const float* u = (const float*)d_in[0];
    const float* W = (const float*)d_in[1];
    float* out = (float*)d_out;
    const size_t need = (size_t)(W_ELEMS + U_ELEMS) * sizeof(__half);
    if (ws_size >= need) {
        __half* Wh = (__half*)d_ws;
        __half* uh = (__half*)((char*)d_ws + (size_t)W_ELEMS * sizeof(__half));
        cvt_kernel<<<dim3(WBLKS + UBLKS), dim3(256), 0, stream>>>(
            W, u, (unsigned*)Wh, (__half2*)uh);
        digitcaps_kernel<true><<<dim3(128, 10), dim3(NT), 0, stream>>>(
            nullptr, nullptr, uh, Wh, out);
    } else {
        digitcaps_kernel<false><<<dim3(128, 10), dim3(NT), 0, stream>>>(
            u, W, nullptr, nullptr, out);
    }
}

// Round 19
// 114.282 us; speedup vs baseline: 1.1131x; 1.0101x over previous
//
#include <hip/hip_runtime.h>
#include <hip/hip_fp16.h>

#define Bsz 256
#define Nn  1152
#define Kk  10
#define NT  768      // 12 waves/block; LDS exactly 80 KB -> 2 blocks/CU = 24 waves
#define NW  12
#define S4  1154     // uint stride per o-pair row (mod 32 = 2; uint2-aligned)

#define W_ELEMS (Kk*Nn*128)     // 1474560
#define U_ELEMS (Bsz*Nn*8)      // 2359296
#define WCELLS  (Kk*Nn)         // 11520 cells of 8x16
#define WBLKS   (WCELLS/16)     // 720 transpose blocks
#define UBLKS   (U_ELEMS/8/256) // 1152 u-convert blocks

typedef _Float16 hf2_t __attribute__((ext_vector_type(2)));

static __device__ __forceinline__ unsigned pkh2(float x, float y) {
    __half2 h = __floats2half2_rn(x, y);
    return *reinterpret_cast<unsigned*>(&h);
}
// v_dot2_f32_f16: c += a.lo*b.lo + a.hi*b.hi (f32 accumulate, 1 inst)
static __device__ __forceinline__ float fdot2u(unsigned a, unsigned b, float c) {
    union { unsigned u; hf2_t h; } A, B;
    A.u = a; B.u = b;
    return __builtin_amdgcn_fdot2(A.h, B.h, c, false);
}
// Within-wave LDS write->read ordering (no s_barrier for wave-local data)
static __device__ __forceinline__ void wave_lds_fence() {
    __builtin_amdgcn_sched_barrier(0);
    asm volatile("s_waitcnt lgkmcnt(0)" ::: "memory");
    __builtin_amdgcn_sched_barrier(0);
}

#define PERM_LO 0x01000504u   // perm(a,b,LO) = half2(lo = lo16(a), hi = lo16(b))
#define PERM_HI 0x03020706u
#define ONE2    0x3C003C00u   // half2(1, 1)

// W: fp32 [K][N][8 i][16 o] -> Wh: fp16, per-cell transposed AND oh-interleaved:
// the uint4 (4 half2 i-pairs) for o-row `o` sits at cell slot (o&7)*2 + (o>>3).
// Phase-1 thread (pr, oh) load j then reads slot j*2+oh -> lane-pair addresses
// contiguous 32 B (R16's coalescing) while staying dot2-ready (R17's math).
__global__ void cvt_kernel(const float* __restrict__ W, const float* __restrict__ u,
                           unsigned* __restrict__ Wh, __half2* __restrict__ uh) {
    const int t = threadIdx.x;
    if ((int)blockIdx.x < WBLKS) {
        __shared__ float ws[16 * 132];
        const size_t base = (size_t)blockIdx.x * (16 * 128);
        const float4* p = (const float4*)(W + base) + t * 2;
        const float4 x = p[0], y = p[1];
        {
            const int e = t * 8;
            float* d = ws + (e >> 7) * 132 + (e & 127);
            d[0]=x.x; d[1]=x.y; d[2]=x.z; d[3]=x.w;
            d[4]=y.x; d[5]=y.y; d[6]=y.z; d[7]=y.w;
        }
        __syncthreads();
        const int c = t >> 4, o = t & 15;        // one o-row per thread
        const float* s = ws + c * 132 + o;
        uint4 r;
        r.x = pkh2(s[0*16], s[1*16]);
        r.y = pkh2(s[2*16], s[3*16]);
        r.z = pkh2(s[4*16], s[5*16]);
        r.w = pkh2(s[6*16], s[7*16]);
        const int slot = (o & 7) * 2 + (o >> 3);         // oh-interleaved slot
        *(uint4*)(Wh + (((size_t)blockIdx.x * 16 + c) * 16 + slot) * 4) = r;
    } else {
        const int j = ((int)blockIdx.x - WBLKS) * 256 + t;   // < 294912
        const float4* p = (const float4*)u + (size_t)j * 2;
        __half2* o = uh + (size_t)j * 4;
        const float4 a = p[0], b = p[1];
        o[0] = __floats2half2_rn(a.x, a.y);
        o[1] = __floats2half2_rn(a.z, a.w);
        o[2] = __floats2half2_rn(b.x, b.y);
        o[3] = __floats2half2_rn(b.z, b.w);
    }
}

// One block per (b-pair, k), 12 waves (R16/R18-verified structure, 58 us). Wave w
// owns rows n = 96w + 32rr + pr. Phase 1: W loaded once for BOTH b's
// (oh-interleaved transposed layout: 32B-contiguous lane pairs, perm-free dot2).
// ROUND-19: s-scan column assignment n0 = 96w + 2(cc + 6 g_s) — same coverage,
// bank index 2 j_s + 12 g_s instead of 2 (j_s + g_s): worst-case LDS conflict
// drops 8-way -> ~2-way (R16/R18 showed 3.9M SQ_LDS_BANK_CONFLICT from this).
// Everything else byte-identical to R18.
template<bool HALF>
__global__ __launch_bounds__(NT, 6)
void digitcaps_kernel(const float* __restrict__ u32, const float* __restrict__ W32,
                      const __half* __restrict__ uh, const __half* __restrict__ Wh,
                      float* __restrict__ out)
{
    const int t    = threadIdx.x;
    const int lane = t & 63;
    const int wav  = t >> 6;             // 0..11
    const int oh   = lane & 1;
    const int pr   = lane >> 1;          // 0..31
    const int bg   = blockIdx.x;         // 0..127
    const int k    = blockIdx.y;         // 0..9
    const int b0   = 2 * bg;
    const int b1   = 2 * bg + 1;

    __shared__ unsigned uhS2[2][8][S4];      // 73856 B  [b][o-pair row][col n]
    __shared__ unsigned cSu[2][Nn / 2];      // 4608 B   [b] e per n (half), uint-paired
    __shared__ float    redS[2][2][NW][18];  // 3456 B   [buf][b][wav][s0..15, d, m_w]
    // total exactly 81920 B -> 2 blocks/CU (24 waves) iff VGPR <= 85

    // ---------------- Phase 1: u_hat = u . W for BOTH b's, W loaded once ----------------
    #pragma unroll
    for (int rr = 0; rr < 3; ++rr) {
        const int n = 96 * wav + 32 * rr + pr;
        float a0[8], a1[8];
        if (HALF) {
            const uint4 uq0 = *(const uint4*)(uh + ((size_t)b0 * Nn + n) * 8);
            const uint4 uq1 = *(const uint4*)(uh + ((size_t)b1 * Nn + n) * 8);
            // cell = 16 uint4, oh-interleaved: load j for this thread = slot 2j+oh.
            const uint4* wp = (const uint4*)Wh + ((size_t)(k * Nn + n)) * 16;
            #pragma unroll
            for (int o = 0; o < 8; ++o) {            // o = local row j; global row 8*oh+o
                const uint4 w = wp[2 * o + oh];
                a0[o] = fdot2u(w.w, uq0.w, fdot2u(w.z, uq0.z,
                        fdot2u(w.y, uq0.y, fdot2u(w.x, uq0.x, 0.f))));
                a1[o] = fdot2u(w.w, uq1.w, fdot2u(w.z, uq1.z,
                        fdot2u(w.y, uq1.y, fdot2u(w.x, uq1.x, 0.f))));
            }
        } else {
            float ua0[8], ua1[8];
            const float4* up0 = (const float4*)(u32 + ((size_t)b0 * Nn + n) * 8);
            const float4* up1 = (const float4*)(u32 + ((size_t)b1 * Nn + n) * 8);
            const float4 x0 = up0[0], x1 = up0[1];
            const float4 y0 = up1[0], y1 = up1[1];
            ua0[0]=x0.x; ua0[1]=x0.y; ua0[2]=x0.z; ua0[3]=x0.w;
            ua0[4]=x1.x; ua0[5]=x1.y; ua0[6]=x1.z; ua0[7]=x1.w;
            ua1[0]=y0.x; ua1[1]=y0.y; ua1[2]=y0.z; ua1[3]=y0.w;
            ua1[4]=y1.x; ua1[5]=y1.y; ua1[6]=y1.z; ua1[7]=y1.w;
            #pragma unroll
            for (int o = 0; o < 8; ++o) { a0[o] = 0.f; a1[o] = 0.f; }
            #pragma unroll
            for (int i = 0; i < 8; ++i) {
                const float4* wp = (const float4*)(W32 + ((size_t)k * Nn + n) * 128) + oh * 2 + i * 4;
                const float4 w0 = wp[0], w1 = wp[1];
                float wv[8];
                wv[0]=w0.x; wv[1]=w0.y; wv[2]=w0.z; wv[3]=w0.w;
                wv[4]=w1.x; wv[5]=w1.y; wv[6]=w1.z; wv[7]=w1.w;
                const float x = ua0[i], y = ua1[i];
                #pragma unroll
                for (int o = 0; o < 8; ++o) { a0[o] += x * wv[o]; a1[o] += y * wv[o]; }
            }
        }
        #pragma unroll
        for (int jj = 0; jj < 4; ++jj) {
            uhS2[0][oh * 4 + jj][n] = pkh2(a0[2*jj], a0[2*jj+1]);
            uhS2[1][oh * 4 + jj][n] = pkh2(a1[2*jj], a1[2*jj+1]);
        }
    }
    wave_lds_fence();   // each wave's scans read only its own 96-row region

    // ---------------- Phase 2: routing (lane parity = which b it routes) ----------------
    float lg[3] = {0.f, 0.f, 0.f};   // logits for this lane's b (= oh) rows
    unsigned vhsel[8];               // v for b = oh, packed half2 (all 8 o-pairs)
    const int j_s = lane & 7;
    const int g_s = lane >> 3;

    #pragma unroll
    for (int it = 0; it < 3; ++it) {
        float m_w = 0.f;
        if (it > 0) {
            // ---- a-scan: lane routes its b over its pair's 3 rows (LDS full-o reads) ----
            #pragma unroll
            for (int rr = 0; rr < 3; ++rr) {
                const int n = 96 * wav + 32 * rr + pr;
                float acc = 0.f;
                #pragma unroll
                for (int jj = 0; jj < 8; ++jj)
                    acc = fdot2u(uhS2[oh][jj][n], vhsel[jj], acc);
                lg[rr] += acc;
            }
            // ---- per-wave per-b max: parity-preserving reduce (offsets 2..32) ----
            float m = fmaxf(fmaxf(lg[0], lg[1]), lg[2]);
            #pragma unroll
            for (int off = 2; off <= 32; off <<= 1)
                m = fmaxf(m, __shfl_xor(m, off));
            m_w = m;                 // even lanes: m_b0; odd lanes: m_b1
            // ---- e -> cSu[oh] (wave-local; e <= 1, fp16-safe) ----
            #pragma unroll
            for (int rr = 0; rr < 3; ++rr) {
                const int n = 96 * wav + 32 * rr + pr;
                ((__half*)cSu[oh])[n] = __float2half(__expf(lg[rr] - m_w));
            }
            wave_lds_fence();        // readers are this same wave
        }

        // ---- s-scan: BOTH b's over wave's 96 rows, pairs (n0, n0+1) ----
        // col assignment cc + 6*g_s (bank-despread): bank = 2 j_s + 12 g_s mod 32
        float2 sp0 = {0.f, 0.f}, sp1 = {0.f, 0.f};
        float dp0 = 0.f, dp1 = 0.f;
        #pragma unroll
        for (int cc = 0; cc < 6; ++cc) {
            const int n0 = 96 * wav + 2 * (cc + 6 * g_s);
            unsigned cp0, cp1;
            if (it == 0) { cp0 = ONE2; cp1 = ONE2; }
            else { cp0 = cSu[0][n0 >> 1]; cp1 = cSu[1][n0 >> 1]; }
            const uint2 q0 = *(const uint2*)&uhS2[0][j_s][n0];
            const uint2 q1 = *(const uint2*)&uhS2[1][j_s][n0];
            const unsigned px0 = __builtin_amdgcn_perm(q0.x, q0.y, PERM_LO);
            const unsigned py0 = __builtin_amdgcn_perm(q0.x, q0.y, PERM_HI);
            const unsigned px1 = __builtin_amdgcn_perm(q1.x, q1.y, PERM_LO);
            const unsigned py1 = __builtin_amdgcn_perm(q1.x, q1.y, PERM_HI);
            sp0.x = fdot2u(px0, cp0, sp0.x);
            sp0.y = fdot2u(py0, cp0, sp0.y);
            sp1.x = fdot2u(px1, cp1, sp1.x);
            sp1.y = fdot2u(py1, cp1, sp1.y);
            dp0   = fdot2u(cp0, ONE2, dp0);
            dp1   = fdot2u(cp1, ONE2, dp1);
        }
        #pragma unroll
        for (int off = 8; off <= 32; off <<= 1) {
            sp0.x += __shfl_xor(sp0.x, off);
            sp0.y += __shfl_xor(sp0.y, off);
            sp1.x += __shfl_xor(sp1.x, off);
            sp1.y += __shfl_xor(sp1.y, off);
            dp0   += __shfl_xor(dp0,   off);
            dp1   += __shfl_xor(dp1,   off);
        }
        const int buf = it & 1;
        if (lane < 8) {
            redS[buf][0][wav][2 * j_s    ] = sp0.x;
            redS[buf][0][wav][2 * j_s + 1] = sp0.y;
            redS[buf][1][wav][2 * j_s    ] = sp1.x;
            redS[buf][1][wav][2 * j_s + 1] = sp1.y;
        }
        if (lane == 0)
            *(float2*)&redS[buf][0][wav][16] = make_float2(dp0, m_w);  // m_w = m_b0 here
        if (lane == 1)
            *(float2*)&redS[buf][1][wav][16] = make_float2(dp1, m_w);  // m_w = m_b1 here
        __syncthreads();                               // the ONLY barrier per iter

        // ---- finalize: per-b cross-wave rescale + squash (redundant per wave) ----
        if (it < 2 || wav == 0) {
            const int bsel = (lane >> 4) & 1;
            const int o    = lane & 15;
            float M = redS[buf][bsel][0][17];
            #pragma unroll
            for (int w = 1; w < NW; ++w) M = fmaxf(M, redS[buf][bsel][w][17]);
            float s = 0.f, d = 0.f;
            #pragma unroll
            for (int w = 0; w < NW; ++w) {
                const float2 dm = *(const float2*)&redS[buf][bsel][w][16];
                const float sc = (it == 0) ? 1.f : __expf(dm.y - M);
                s += sc * redS[buf][bsel][w][o];
                d += sc * dm.x;
            }
            s /= d;
            float s2 = s * s;
            #pragma unroll
            for (int off = 1; off <= 8; off <<= 1) s2 += __shfl_xor(s2, off);
            const float scale = (s2 / (1.f + s2)) * rsqrtf(fmaxf(s2, 1e-30f));
            const float v = s * scale;
            if (it == 2) {
                if (wav == 0 && lane < 32)
                    out[((size_t)k * Bsz + b0 + bsel) * 16 + o] = v;
            } else {
                // lane's own b half: v_b0 in lanes 0-15, v_b1 in lanes 16-31.
                // runtime shfl lane index ok; array subscript jj static.
                #pragma unroll
                for (int jj = 0; jj < 8; ++jj)
                    vhsel[jj] = pkh2(__shfl(v, 16 * oh + 2 * jj),
                                     __shfl(v, 16 * oh + 2 * jj + 1));
            }
        }
    }
}

extern "C" void kernel_launch(void* const* d_in, const int* in_sizes, int n_in,
                              void* d_out, int out_size, void* d_ws, size_t ws_size,
                              hipStream_t stream) {
    const float* u = (const float*)d_in[0];
    const float* W = (const float*)d_in[1];
    float* out = (float*)d_out;
    const size_t need = (size_t)(W_ELEMS + U_ELEMS) * sizeof(__half);
    if (ws_size >= need) {
        __half* Wh = (__half*)d_ws;
        __half* uh = (__half*)((char*)d_ws + (size_t)W_ELEMS * sizeof(__half));
        cvt_kernel<<<dim3(WBLKS + UBLKS), dim3(256), 0, stream>>>(
            W, u, (unsigned*)Wh, (__half2*)uh);
        digitcaps_kernel<true><<<dim3(128, 10), dim3(NT), 0, stream>>>(
            nullptr, nullptr, uh, Wh, out);
    } else {
        digitcaps_kernel<false><<<dim3(128, 10), dim3(NT), 0, stream>>>(
            u, W, nullptr, nullptr, out);
    }
}